// Round 3
// baseline (183.726 us; speedup 1.0000x reference)
//
#include <hip/hip_runtime.h>
#include <hip/hip_bf16.h>
#include <hip/hip_fp16.h>

typedef _Float16 half8 __attribute__((ext_vector_type(8)));
typedef _Float16 half4 __attribute__((ext_vector_type(4)));
typedef float floatx4 __attribute__((ext_vector_type(4)));

#define BATCH   4096
#define NIN     1024
#define NODES   4095
#define NPAD    4096
#define NOUT    1024
#define NLEAF   4096

__device__ __forceinline__ void gload_lds16(const void* g, void* l) {
    __builtin_amdgcn_global_load_lds(
        (const __attribute__((address_space(1))) void*)g,
        (__attribute__((address_space(3))) void*)l, 16, 0, 0);
}

// ---------- convert f32 -> f16, zero-padding past nsrc ----------
__global__ void k_f32_to_f16_pad(const float* __restrict__ src,
                                 _Float16* __restrict__ dst, int n, int nsrc) {
    int i = (blockIdx.x * blockDim.x + threadIdx.x) * 4;
    if (i >= n) return;
    float4 v;
    if (i < nsrc) v = *(const float4*)(src + i);
    else          v = make_float4(0.f, 0.f, 0.f, 0.f);
    half4 h;
    h.x = (_Float16)v.x; h.y = (_Float16)v.y;
    h.z = (_Float16)v.z; h.w = (_Float16)v.w;
    *(half4*)(dst + i) = h;
}

// ---------- transpose leaf [NLEAF][NOUT] f32 -> leafT [NOUT][NLEAF] f16 ----------
__global__ void k_transpose_f16(const float* __restrict__ src,
                                _Float16* __restrict__ dst) {
    __shared__ _Float16 t[32][33];
    int l0 = blockIdx.x * 32, o0 = blockIdx.y * 32;
    int tx = threadIdx.x & 31, ty = threadIdx.x >> 5;  // 32 x 8
#pragma unroll
    for (int i = 0; i < 4; i++) {
        int l = l0 + ty + i * 8;
        t[ty + i * 8][tx] = (_Float16)src[(size_t)l * NOUT + o0 + tx];
    }
    __syncthreads();
#pragma unroll
    for (int i = 0; i < 4; i++) {
        int o = o0 + ty + i * 8;
        dst[(size_t)o * NLEAF + l0 + tx] = t[tx][ty + i * 8];
    }
}

// ---------- 128x128 gemm_bt: C = A(MxK) * B(NxK)^T ----------
// 4-deep LDS ring pipeline, counted vmcnt (T3+T4): raw s_barrier (no vmcnt drain),
// stage kt+3 issued after the barrier, s_waitcnt vmcnt(8) keeps 2 stages in flight.
// Safety: stage i+3 overwrites buf[(i+3)&3]=buf[(i-1)&3]; issue is after iter-i's
// barrier, which every wave reaches only after its iter-(i-1) ds_reads retired
// (lgkmcnt(0) precedes that iter's MFMAs in program order).
// LDS chunk swizzle (both sides, rule 21): chunk c stored at pos c^((row>>1)&3);
// write side via pre-swizzled GLOBAL source (LDS dest linear), read side same XOR.
// EPILOGUE==1: C fp16 = sigmoid(acc + bias[col]) (gate GEMM)
// EPILOGUE==0: C f32 = acc (leaf GEMM)
template <int EPILOGUE>
__launch_bounds__(256)
__global__ void gemm_bt(const _Float16* __restrict__ A,
                        const _Float16* __restrict__ Bm,
                        const float* __restrict__ bias,
                        void* __restrict__ C,
                        int M, int N, int K, int ldc) {
    __shared__ __align__(16) _Float16 As[4][128 * 32];
    __shared__ __align__(16) _Float16 Bs[4][128 * 32];
    const int tid  = threadIdx.x;
    const int lane = tid & 63;
    const int wave = tid >> 6;
    const int wr = wave >> 1, wc = wave & 1;
    const int m0 = blockIdx.y * 128;
    const int n0 = blockIdx.x * 128;

    floatx4 acc[4][4] = {};

    // staging: thread tid covers LDS 16B slot tid (row=tid>>2, pos=tid&3) and slot tid+256.
    const int rA0 = tid >> 2;                                // local row 0..63 (2nd issue: +64)
    const int cg  = ((tid & 3) ^ ((tid >> 3) & 3)) * 8;      // pre-swizzled source chunk

    const _Float16* Ag  = A  + (size_t)(m0 + rA0) * K + cg;
    const _Float16* Ag2 = Ag + (size_t)64 * K;
    const _Float16* Bg  = Bm + (size_t)(n0 + rA0) * K + cg;
    const _Float16* Bg2 = Bg + (size_t)64 * K;

    const int arow = wr * 64 + (lane & 15);
    const int brow = wc * 64 + (lane & 15);
    const int csel = lane >> 4;            // lane's desired k-chunk

    const int NITER = K >> 5;

    // prologue: issue stages 0..2 into bufs 0..2 (12 loads in flight)
#pragma unroll
    for (int s = 0; s < 3; ++s) {
        const int kt = s * 32;
        gload_lds16(Ag  + kt, &As[s][tid * 8]);
        gload_lds16(Ag2 + kt, &As[s][2048 + tid * 8]);
        gload_lds16(Bg  + kt, &Bs[s][tid * 8]);
        gload_lds16(Bg2 + kt, &Bs[s][2048 + tid * 8]);
    }

    for (int i = 0; i < NITER; ++i) {
        // wait until stage i landed: leave stages i+1,i+2 in flight (4 loads each)
        const int ahead = NITER - 1 - i;
        if (ahead >= 2)      asm volatile("s_waitcnt vmcnt(8)" ::: "memory");
        else if (ahead == 1) asm volatile("s_waitcnt vmcnt(4)" ::: "memory");
        else                 asm volatile("s_waitcnt vmcnt(0)" ::: "memory");
        __builtin_amdgcn_sched_barrier(0);
        __builtin_amdgcn_s_barrier();      // all waves' stage-i loads landed
        __builtin_amdgcn_sched_barrier(0);

        // issue stage i+3 (overwrites buf read in iter i-1; safe past the barrier)
        const int is = i + 3;
        if (is < NITER) {
            const int kt = is * 32;
            const int b  = is & 3;
            gload_lds16(Ag  + kt, &As[b][tid * 8]);
            gload_lds16(Ag2 + kt, &As[b][2048 + tid * 8]);
            gload_lds16(Bg  + kt, &Bs[b][tid * 8]);
            gload_lds16(Bg2 + kt, &Bs[b][2048 + tid * 8]);
        }

        const _Float16* Ab = As[i & 3];
        const _Float16* Bb = Bs[i & 3];
        half8 af[4], bf[4];
#pragma unroll
        for (int ii = 0; ii < 4; ii++) {
            int row = arow + ii * 16;
            int pos = (csel ^ ((row >> 1) & 3)) * 8;
            af[ii] = *(const half8*)(&Ab[row * 32 + pos]);
        }
#pragma unroll
        for (int j = 0; j < 4; j++) {
            int row = brow + j * 16;
            int pos = (csel ^ ((row >> 1) & 3)) * 8;
            bf[j] = *(const half8*)(&Bb[row * 32 + pos]);
        }
#pragma unroll
        for (int ii = 0; ii < 4; ii++)
#pragma unroll
            for (int j = 0; j < 4; j++)
                acc[ii][j] = __builtin_amdgcn_mfma_f32_16x16x32_f16(
                    af[ii], bf[j], acc[ii][j], 0, 0, 0);
        __builtin_amdgcn_sched_barrier(0);  // fence iterations (no cross-iter sinking)
    }

    const int crow0 = m0 + wr * 64 + (lane >> 4) * 4;
    const int ccol0 = n0 + wc * 64 + (lane & 15);
#pragma unroll
    for (int i = 0; i < 4; i++) {
#pragma unroll
        for (int j = 0; j < 4; j++) {
            int col = ccol0 + j * 16;
#pragma unroll
            for (int r = 0; r < 4; r++) {
                int row = crow0 + i * 16 + r;
                float v = acc[i][j][r];
                if (EPILOGUE == 1) {
                    float bb = (col < NODES) ? bias[col] : 0.f;
                    float z = v + bb;
                    float gg = 1.f / (1.f + __expf(-z));
                    ((_Float16*)C)[(size_t)row * ldc + col] = (_Float16)gg;
                } else {
                    ((float*)C)[(size_t)row * ldc + col] = v;
                }
            }
        }
    }
}

// ---------- probs: per batch row, hierarchical tree-product expansion ----------
__global__ void k_probs(const _Float16* __restrict__ g,
                        _Float16* __restrict__ probs) {
    __shared__ float gs[NPAD];
    const int b = blockIdx.x;
    const _Float16* grow = g + (size_t)b * NPAD;
#pragma unroll
    for (int it = 0; it < 2; it++) {
        int i = threadIdx.x + it * 256;   // i in [0,512): 8 halves each
        half8 v = *(const half8*)(grow + i * 8);
#pragma unroll
        for (int j = 0; j < 8; j++) gs[i * 8 + j] = (float)v[j];
    }
    __syncthreads();
    const int t = threadIdx.x;  // subtree over leaves [t*16, t*16+16)
    float p = 1.f;
#pragma unroll
    for (int d = 0; d < 8; d++) {
        int node = (1 << d) - 1 + (t >> (8 - d));
        float gg = gs[node];
        int bit = (t >> (7 - d)) & 1;
        p *= bit ? gg : (1.f - gg);
    }
    float p9[2], p10[4], p11[8], p12[16];
    {
        float gg = gs[255 + t];
        p9[0] = p * (1.f - gg); p9[1] = p * gg;
    }
#pragma unroll
    for (int i = 0; i < 2; i++) {
        float gg = gs[511 + 2 * t + i];
        p10[2 * i] = p9[i] * (1.f - gg); p10[2 * i + 1] = p9[i] * gg;
    }
#pragma unroll
    for (int i = 0; i < 4; i++) {
        float gg = gs[1023 + 4 * t + i];
        p11[2 * i] = p10[i] * (1.f - gg); p11[2 * i + 1] = p10[i] * gg;
    }
#pragma unroll
    for (int i = 0; i < 8; i++) {
        float gg = gs[2047 + 8 * t + i];
        p12[2 * i] = p11[i] * (1.f - gg); p12[2 * i + 1] = p11[i] * gg;
    }
    half8 o0, o1;
#pragma unroll
    for (int j = 0; j < 8; j++) { o0[j] = (_Float16)p12[j]; o1[j] = (_Float16)p12[8 + j]; }
    _Float16* pr = probs + (size_t)b * NLEAF + t * 16;
    *(half8*)(pr) = o0;
    *(half8*)(pr + 8) = o1;
}

extern "C" void kernel_launch(void* const* d_in, const int* in_sizes, int n_in,
                              void* d_out, int out_size, void* d_ws, size_t ws_size,
                              hipStream_t stream) {
    (void)in_sizes; (void)n_in; (void)out_size; (void)ws_size;
    const float* x    = (const float*)d_in[0];
    const float* W    = (const float*)d_in[1];
    const float* bias = (const float*)d_in[2];
    const float* leaf = (const float*)d_in[3];
    float* out = (float*)d_out;

    _Float16* xh    = (_Float16*)d_ws;                       // 8 MB
    _Float16* Wh    = xh + (size_t)BATCH * NIN;              // 8 MB
    _Float16* leafT = Wh + (size_t)NPAD * NIN;               // 8 MB
    _Float16* g     = leafT + (size_t)NOUT * NLEAF;          // 32 MB
    _Float16* probs = g + (size_t)BATCH * NPAD;              // 32 MB

    k_f32_to_f16_pad<<<(BATCH * NIN / 4 + 255) / 256, 256, 0, stream>>>(
        x, xh, BATCH * NIN, BATCH * NIN);
    k_f32_to_f16_pad<<<(NPAD * NIN / 4 + 255) / 256, 256, 0, stream>>>(
        W, Wh, NPAD * NIN, NODES * NIN);
    k_transpose_f16<<<dim3(NLEAF / 32, NOUT / 32), 256, 0, stream>>>(leaf, leafT);

    gemm_bt<1><<<dim3(NPAD / 128, BATCH / 128), 256, 0, stream>>>(
        xh, Wh, bias, (void*)g, BATCH, NPAD, NIN, NPAD);

    k_probs<<<BATCH, 256, 0, stream>>>(g, probs);

    gemm_bt<0><<<dim3(NOUT / 128, BATCH / 128), 256, 0, stream>>>(
        probs, leafT, nullptr, (void*)out, BATCH, NOUT, NLEAF, NOUT);
}

// Round 4
// 166.623 us; speedup vs baseline: 1.1026x; 1.1026x over previous
//
#include <hip/hip_runtime.h>
#include <hip/hip_bf16.h>
#include <hip/hip_fp16.h>

typedef _Float16 half8 __attribute__((ext_vector_type(8)));
typedef _Float16 half4 __attribute__((ext_vector_type(4)));
typedef float floatx4 __attribute__((ext_vector_type(4)));

#define BATCH   4096
#define NIN     1024
#define NODES   4095
#define NPAD    4096
#define NOUT    1024
#define NLEAF   4096
#define SPLITK  4

__device__ __forceinline__ void gload_lds16(const void* g, void* l) {
    __builtin_amdgcn_global_load_lds(
        (const __attribute__((address_space(1))) void*)g,
        (__attribute__((address_space(3))) void*)l, 16, 0, 0);
}

// ---------- convert f32 -> f16, zero-padding past nsrc ----------
__global__ void k_f32_to_f16_pad(const float* __restrict__ src,
                                 _Float16* __restrict__ dst, int n, int nsrc) {
    int i = (blockIdx.x * blockDim.x + threadIdx.x) * 4;
    if (i >= n) return;
    float4 v;
    if (i < nsrc) v = *(const float4*)(src + i);
    else          v = make_float4(0.f, 0.f, 0.f, 0.f);
    half4 h;
    h.x = (_Float16)v.x; h.y = (_Float16)v.y;
    h.z = (_Float16)v.z; h.w = (_Float16)v.w;
    *(half4*)(dst + i) = h;
}

// ---------- transpose leaf [NLEAF][NOUT] f32 -> leafT [NOUT][NLEAF] f16 ----------
__global__ void k_transpose_f16(const float* __restrict__ src,
                                _Float16* __restrict__ dst) {
    __shared__ _Float16 t[32][33];
    int l0 = blockIdx.x * 32, o0 = blockIdx.y * 32;
    int tx = threadIdx.x & 31, ty = threadIdx.x >> 5;  // 32 x 8
#pragma unroll
    for (int i = 0; i < 4; i++) {
        int l = l0 + ty + i * 8;
        t[ty + i * 8][tx] = (_Float16)src[(size_t)l * NOUT + o0 + tx];
    }
    __syncthreads();
#pragma unroll
    for (int i = 0; i < 4; i++) {
        int o = o0 + ty + i * 8;
        dst[(size_t)o * NLEAF + l0 + tx] = t[tx][ty + i * 8];
    }
}

// ---------- 128x128 gemm_bt: C += A(MxK-slice) * B(NxK-slice)^T ----------
// R2-proven interior: 2-buffer LDS pipeline, one __syncthreads per K-step,
// zero-conflict chunk swizzle (both-sides, rule 21): chunk c at pos c^((row>>1)&3);
// write side via pre-swizzled GLOBAL source (LDS dest linear), read side same XOR.
// blockIdx.z selects K-slice [z*Klen, (z+1)*Klen); K is the full row stride.
// EPILOGUE==1: C fp16 = sigmoid(acc + bias[col])        (gate GEMM, z=0 only)
// EPILOGUE==2: C fp16 partial at C + z*M*ldc            (leaf GEMM split-K)
template <int EPILOGUE>
__launch_bounds__(256)
__global__ void gemm_bt(const _Float16* __restrict__ A,
                        const _Float16* __restrict__ Bm,
                        const float* __restrict__ bias,
                        void* __restrict__ C,
                        int M, int N, int K, int ldc, int Klen) {
    __shared__ __align__(16) _Float16 As[2][128 * 32];
    __shared__ __align__(16) _Float16 Bs[2][128 * 32];
    const int tid  = threadIdx.x;
    const int lane = tid & 63;
    const int wave = tid >> 6;
    const int wr = wave >> 1, wc = wave & 1;
    const int m0 = blockIdx.y * 128;
    const int n0 = blockIdx.x * 128;
    const int k0 = blockIdx.z * Klen;

    floatx4 acc[4][4] = {};

    // staging: thread tid covers LDS 16B slot tid (row=tid>>2, pos=tid&3) and slot tid+256.
    const int rA0 = tid >> 2;                                // local row 0..63 (2nd issue: +64)
    const int cg  = ((tid & 3) ^ ((tid >> 3) & 3)) * 8;      // pre-swizzled source chunk

    const _Float16* Ag  = A  + (size_t)(m0 + rA0) * K + k0 + cg;
    const _Float16* Ag2 = Ag + (size_t)64 * K;
    const _Float16* Bg  = Bm + (size_t)(n0 + rA0) * K + k0 + cg;
    const _Float16* Bg2 = Bg + (size_t)64 * K;

    _Float16* AsW[2] = { &As[0][tid * 8], &As[1][tid * 8] };
    _Float16* BsW[2] = { &Bs[0][tid * 8], &Bs[1][tid * 8] };

    const int arow = wr * 64 + (lane & 15);
    const int brow = wc * 64 + (lane & 15);
    const int csel = lane >> 4;            // lane's desired k-chunk

    // prologue: stage tile 0 into buf 0
    gload_lds16(Ag,  AsW[0]);
    gload_lds16(Ag2, AsW[0] + 2048);
    gload_lds16(Bg,  BsW[0]);
    gload_lds16(Bg2, BsW[0] + 2048);
    __syncthreads();

    int buf = 0;
    for (int kt = 0; kt < Klen; kt += 32) {
        if (kt + 32 < Klen) {  // stage next tile into the other buffer
            gload_lds16(Ag  + kt + 32, AsW[buf ^ 1]);
            gload_lds16(Ag2 + kt + 32, AsW[buf ^ 1] + 2048);
            gload_lds16(Bg  + kt + 32, BsW[buf ^ 1]);
            gload_lds16(Bg2 + kt + 32, BsW[buf ^ 1] + 2048);
        }
        half8 af[4], bf[4];
#pragma unroll
        for (int i = 0; i < 4; i++) {
            int row = arow + i * 16;
            int pos = (csel ^ ((row >> 1) & 3)) * 8;
            af[i] = *(const half8*)(&As[buf][row * 32 + pos]);
        }
#pragma unroll
        for (int j = 0; j < 4; j++) {
            int row = brow + j * 16;
            int pos = (csel ^ ((row >> 1) & 3)) * 8;
            bf[j] = *(const half8*)(&Bs[buf][row * 32 + pos]);
        }
#pragma unroll
        for (int i = 0; i < 4; i++)
#pragma unroll
            for (int j = 0; j < 4; j++)
                acc[i][j] = __builtin_amdgcn_mfma_f32_16x16x32_f16(
                    af[i], bf[j], acc[i][j], 0, 0, 0);
        __syncthreads();  // drains next-tile stage (vmcnt) + this tile's ds_reads (lgkm)
        buf ^= 1;
    }

    const int crow0 = m0 + wr * 64 + (lane >> 4) * 4;
    const int ccol0 = n0 + wc * 64 + (lane & 15);
    _Float16* Cp = (_Float16*)C + (EPILOGUE == 2 ? (size_t)blockIdx.z * M * ldc : 0);
#pragma unroll
    for (int i = 0; i < 4; i++) {
#pragma unroll
        for (int j = 0; j < 4; j++) {
            int col = ccol0 + j * 16;
#pragma unroll
            for (int r = 0; r < 4; r++) {
                int row = crow0 + i * 16 + r;
                float v = acc[i][j][r];
                if (EPILOGUE == 1) {
                    float bb = (col < NODES) ? bias[col] : 0.f;
                    float z = v + bb;
                    float gg = 1.f / (1.f + __expf(-z));
                    Cp[(size_t)row * ldc + col] = (_Float16)gg;
                } else {
                    Cp[(size_t)row * ldc + col] = (_Float16)v;
                }
            }
        }
    }
}

// ---------- reduce 4 fp16 partials -> f32 out ----------
__global__ void k_reduce4(const _Float16* __restrict__ part, float* __restrict__ out) {
    const size_t S = (size_t)BATCH * NOUT;
    size_t i = ((size_t)blockIdx.x * 256 + threadIdx.x) * 8;
    half8 a = *(const half8*)(part + i);
    half8 b = *(const half8*)(part + S + i);
    half8 c = *(const half8*)(part + 2 * S + i);
    half8 d = *(const half8*)(part + 3 * S + i);
    float4 lo, hi;
    lo.x = (float)a[0] + (float)b[0] + (float)c[0] + (float)d[0];
    lo.y = (float)a[1] + (float)b[1] + (float)c[1] + (float)d[1];
    lo.z = (float)a[2] + (float)b[2] + (float)c[2] + (float)d[2];
    lo.w = (float)a[3] + (float)b[3] + (float)c[3] + (float)d[3];
    hi.x = (float)a[4] + (float)b[4] + (float)c[4] + (float)d[4];
    hi.y = (float)a[5] + (float)b[5] + (float)c[5] + (float)d[5];
    hi.z = (float)a[6] + (float)b[6] + (float)c[6] + (float)d[6];
    hi.w = (float)a[7] + (float)b[7] + (float)c[7] + (float)d[7];
    *(float4*)(out + i) = lo;
    *(float4*)(out + i + 4) = hi;
}

// ---------- probs: per batch row, hierarchical tree-product expansion ----------
__global__ void k_probs(const _Float16* __restrict__ g,
                        _Float16* __restrict__ probs) {
    __shared__ float gs[NPAD];
    const int b = blockIdx.x;
    const _Float16* grow = g + (size_t)b * NPAD;
#pragma unroll
    for (int it = 0; it < 2; it++) {
        int i = threadIdx.x + it * 256;   // i in [0,512): 8 halves each
        half8 v = *(const half8*)(grow + i * 8);
#pragma unroll
        for (int j = 0; j < 8; j++) gs[i * 8 + j] = (float)v[j];
    }
    __syncthreads();
    const int t = threadIdx.x;  // subtree over leaves [t*16, t*16+16)
    float p = 1.f;
#pragma unroll
    for (int d = 0; d < 8; d++) {
        int node = (1 << d) - 1 + (t >> (8 - d));
        float gg = gs[node];
        int bit = (t >> (7 - d)) & 1;
        p *= bit ? gg : (1.f - gg);
    }
    float p9[2], p10[4], p11[8], p12[16];
    {
        float gg = gs[255 + t];
        p9[0] = p * (1.f - gg); p9[1] = p * gg;
    }
#pragma unroll
    for (int i = 0; i < 2; i++) {
        float gg = gs[511 + 2 * t + i];
        p10[2 * i] = p9[i] * (1.f - gg); p10[2 * i + 1] = p9[i] * gg;
    }
#pragma unroll
    for (int i = 0; i < 4; i++) {
        float gg = gs[1023 + 4 * t + i];
        p11[2 * i] = p10[i] * (1.f - gg); p11[2 * i + 1] = p10[i] * gg;
    }
#pragma unroll
    for (int i = 0; i < 8; i++) {
        float gg = gs[2047 + 8 * t + i];
        p12[2 * i] = p11[i] * (1.f - gg); p12[2 * i + 1] = p11[i] * gg;
    }
    half8 o0, o1;
#pragma unroll
    for (int j = 0; j < 8; j++) { o0[j] = (_Float16)p12[j]; o1[j] = (_Float16)p12[8 + j]; }
    _Float16* pr = probs + (size_t)b * NLEAF + t * 16;
    *(half8*)(pr) = o0;
    *(half8*)(pr + 8) = o1;
}

extern "C" void kernel_launch(void* const* d_in, const int* in_sizes, int n_in,
                              void* d_out, int out_size, void* d_ws, size_t ws_size,
                              hipStream_t stream) {
    (void)in_sizes; (void)n_in; (void)out_size; (void)ws_size;
    const float* x    = (const float*)d_in[0];
    const float* W    = (const float*)d_in[1];
    const float* bias = (const float*)d_in[2];
    const float* leaf = (const float*)d_in[3];
    float* out = (float*)d_out;

    // ws layout (halves). Long-lived first; partials alias the dead region.
    _Float16* base  = (_Float16*)d_ws;
    _Float16* leafT = base;                                   // [0,8) MB   live: transpose -> leaf GEMM
    _Float16* probs = base + (size_t)4 * 1024 * 1024;         // [8,40) MB  live: k_probs -> leaf GEMM
    _Float16* xh    = base + (size_t)20 * 1024 * 1024;        // [40,48) MB dead after gate GEMM
    _Float16* Wh    = base + (size_t)24 * 1024 * 1024;        // [48,56) MB dead after gate GEMM
    _Float16* g     = base + (size_t)28 * 1024 * 1024;        // [56,88) MB dead after k_probs
    _Float16* part  = xh;                                     // [40,72) MB written by leaf GEMM (after k_probs)

    k_f32_to_f16_pad<<<(BATCH * NIN / 4 + 255) / 256, 256, 0, stream>>>(
        x, xh, BATCH * NIN, BATCH * NIN);
    k_f32_to_f16_pad<<<(NPAD * NIN / 4 + 255) / 256, 256, 0, stream>>>(
        W, Wh, NPAD * NIN, NODES * NIN);
    k_transpose_f16<<<dim3(NLEAF / 32, NOUT / 32), 256, 0, stream>>>(leaf, leafT);

    gemm_bt<1><<<dim3(NPAD / 128, BATCH / 128, 1), 256, 0, stream>>>(
        xh, Wh, bias, (void*)g, BATCH, NPAD, NIN, NPAD, NIN);

    k_probs<<<BATCH, 256, 0, stream>>>(g, probs);

    gemm_bt<2><<<dim3(NOUT / 128, BATCH / 128, SPLITK), 256, 0, stream>>>(
        probs, leafT, nullptr, (void*)part, BATCH, NOUT, NLEAF, NOUT, NLEAF / SPLITK);

    k_reduce4<<<(BATCH * NOUT) / (256 * 8), 256, 0, stream>>>(part, out);
}

// Round 5
// 142.569 us; speedup vs baseline: 1.2887x; 1.1687x over previous
//
#include <hip/hip_runtime.h>
#include <hip/hip_bf16.h>
#include <hip/hip_fp16.h>

typedef _Float16 half8 __attribute__((ext_vector_type(8)));
typedef _Float16 half4 __attribute__((ext_vector_type(4)));
typedef float floatx4 __attribute__((ext_vector_type(4)));

#define BATCH   4096
#define NIN     1024
#define NODES   4095
#define NPAD    4096
#define NOUT    1024
#define NLEAF   4096
#define SPLITK  4

__device__ __forceinline__ void gload_lds16(const void* g, void* l) {
    __builtin_amdgcn_global_load_lds(
        (const __attribute__((address_space(1))) void*)g,
        (__attribute__((address_space(3))) void*)l, 16, 0, 0);
}

// ---------- convert f32 -> f16, zero-padding past nsrc ----------
__global__ void k_f32_to_f16_pad(const float* __restrict__ src,
                                 _Float16* __restrict__ dst, int n, int nsrc) {
    int i = (blockIdx.x * blockDim.x + threadIdx.x) * 4;
    if (i >= n) return;
    float4 v;
    if (i < nsrc) v = *(const float4*)(src + i);
    else          v = make_float4(0.f, 0.f, 0.f, 0.f);
    half4 h;
    h.x = (_Float16)v.x; h.y = (_Float16)v.y;
    h.z = (_Float16)v.z; h.w = (_Float16)v.w;
    *(half4*)(dst + i) = h;
}

// ---------- transpose leaf [NLEAF][NOUT] f32 -> leafT [NOUT][NLEAF] f16 ----------
__global__ void k_transpose_f16(const float* __restrict__ src,
                                _Float16* __restrict__ dst) {
    __shared__ _Float16 t[32][33];
    int l0 = blockIdx.x * 32, o0 = blockIdx.y * 32;
    int tx = threadIdx.x & 31, ty = threadIdx.x >> 5;  // 32 x 8
#pragma unroll
    for (int i = 0; i < 4; i++) {
        int l = l0 + ty + i * 8;
        t[ty + i * 8][tx] = (_Float16)src[(size_t)l * NOUT + o0 + tx];
    }
    __syncthreads();
#pragma unroll
    for (int i = 0; i < 4; i++) {
        int o = o0 + ty + i * 8;
        dst[(size_t)o * NLEAF + l0 + tx] = t[tx][ty + i * 8];
    }
}

// ================= 256x256 8-phase GEMM (C = A * B^T), f16 MFMA ================
// 8 waves (2M x 4N), per-wave output 128x64 with INTERLEAVED rows:
//   rows = qr*128 + wm*64 + fr*16, cols = qc*128 + wn*32 + fc*16
// so phase (qr,qc) reads exactly A-half qr and B-half qc. Gray-code phase order
// (0,0)(0,1)(1,1)(1,0) retires halves one per phase; staging ring runs 6 phases
// ahead of consumption, one half-tile (2 x gload_lds/thread) per phase:
//   iter T: q0->(T+1).Ah1[buf^1]  q1->(T+1).Bh0[buf^1]  q2->(T+2).Ah0[buf]  q3->(T+2).Bh1[buf]
// Single counted gate per K-tile at q3: vmcnt(4) == the 2 half-tiles of T+2 in
// flight; guarantees tile T+1 fully landed before its first ds_read (then 0 at tail).
// LDS chunk swizzle (both-sides, rule 21): 16B chunk c of row r stored at pos
// c ^ (r&7); write side via pre-swizzled GLOBAL source (LDS dest stays linear),
// read side same XOR -> 2-way conflict (free).
// EPILOGUE==1: C fp16 = sigmoid(acc + bias[col])   (gate GEMM)
// EPILOGUE==2: C fp16 partial at C + z*M*ldc       (leaf GEMM split-K)
#define PHASE(QR, QC, STAGE_STMT, GATE_STMT)                                    \
  {                                                                             \
    half8 af[4][2], bf[2][2];                                                   \
    _Pragma("unroll") for (int fr = 0; fr < 4; fr++) {                          \
      const _Float16* ap = &As[buf][QR][(arow + fr * 16) * 64];                 \
      af[fr][0] = *(const half8*)(ap + pA0);                                    \
      af[fr][1] = *(const half8*)(ap + pA1);                                    \
    }                                                                           \
    _Pragma("unroll") for (int fc = 0; fc < 2; fc++) {                          \
      const _Float16* bp = &Bs[buf][QC][(brow + fc * 16) * 64];                 \
      bf[fc][0] = *(const half8*)(bp + pB0);                                    \
      bf[fc][1] = *(const half8*)(bp + pB1);                                    \
    }                                                                           \
    STAGE_STMT;                                                                 \
    __builtin_amdgcn_s_barrier();                                               \
    asm volatile("s_waitcnt lgkmcnt(0)" ::: "memory");                          \
    __builtin_amdgcn_sched_barrier(0);                                          \
    __builtin_amdgcn_s_setprio(1);                                              \
    _Pragma("unroll") for (int kk = 0; kk < 2; kk++)                            \
      _Pragma("unroll") for (int fr = 0; fr < 4; fr++)                          \
        _Pragma("unroll") for (int fc = 0; fc < 2; fc++)                        \
          acc[QR][QC][fr][fc] = __builtin_amdgcn_mfma_f32_16x16x32_f16(         \
              af[fr][kk], bf[fc][kk], acc[QR][QC][fr][fc], 0, 0, 0);            \
    __builtin_amdgcn_s_setprio(0);                                              \
    GATE_STMT;                                                                  \
    __builtin_amdgcn_s_barrier();                                               \
  }

template <int EPILOGUE>
__launch_bounds__(512, 2)
__global__ void gemm256(const _Float16* __restrict__ A,
                        const _Float16* __restrict__ Bm,
                        const float* __restrict__ bias,
                        void* __restrict__ C,
                        int M, int N, int K, int ldc, int Klen) {
    __shared__ __align__(16) _Float16 As[2][2][128 * 64];
    __shared__ __align__(16) _Float16 Bs[2][2][128 * 64];
    const int tid  = threadIdx.x;
    const int lane = tid & 63;
    const int wid  = tid >> 6;       // 0..7
    const int wm   = wid >> 2;       // 0..1
    const int wn   = wid & 3;        // 0..3
    const int m0 = blockIdx.y * 256;
    const int n0 = blockIdx.x * 256;
    const int k0 = blockIdx.z * Klen;
    (void)N;

    floatx4 acc[2][2][4][2] = {};

    // ---- staging geometry: thread stages 16B chunk tid (r=tid>>3,pos=tid&7)
    // and chunk tid+512 (row+64, same pos) of each half-tile; source chunk is
    // pre-swizzled: c = pos ^ (r&7) (row+64 keeps the same XOR).
    const int r1 = tid >> 3;
    const int c1 = (tid & 7) ^ (r1 & 7);
    const _Float16* Abase = A  + (size_t)(m0 + r1) * K + k0 + c1 * 8;
    const _Float16* Bbase = Bm + (size_t)(n0 + r1) * K + k0 + c1 * 8;

    auto stageA = [&](int bufx, int h, int T) {
        const _Float16* s = Abase + (size_t)h * 128 * K + T * 64;
        gload_lds16(s,                    &As[bufx][h][tid * 8]);
        gload_lds16(s + (size_t)64 * K,   &As[bufx][h][4096 + tid * 8]);
    };
    auto stageB = [&](int bufx, int h, int T) {
        const _Float16* s = Bbase + (size_t)h * 128 * K + T * 64;
        gload_lds16(s,                    &Bs[bufx][h][tid * 8]);
        gload_lds16(s + (size_t)64 * K,   &Bs[bufx][h][4096 + tid * 8]);
    };

    // ---- ds_read geometry (within the selected half): fragment row r reads
    // chunk c = kk*4 + (lane>>4) at swizzled pos (c ^ (r&7)); r&7 is invariant
    // across fr (fr*16 = 0 mod 8) so the XOR is a per-thread constant.
    const int l4   = lane >> 4;
    const int arow = wm * 64 + (lane & 15);
    const int brow = wn * 32 + (lane & 15);
    const int pA0 = ((l4)     ^ (arow & 7)) * 8;
    const int pA1 = ((4 + l4) ^ (arow & 7)) * 8;
    const int pB0 = ((l4)     ^ (brow & 7)) * 8;
    const int pB1 = ((4 + l4) ^ (brow & 7)) * 8;

    const int NTt = Klen >> 6;

    // ---- prologue: tile0 fully + tile1's {Ah0,Bh1}; leave tile1's pair in flight
    stageA(0, 0, 0); stageB(0, 0, 0); stageA(0, 1, 0); stageB(0, 1, 0);
    if (NTt > 1) {
        stageA(1, 0, 1); stageB(1, 1, 1);
        asm volatile("s_waitcnt vmcnt(4)" ::: "memory");
    } else {
        asm volatile("s_waitcnt vmcnt(0)" ::: "memory");
    }
    __builtin_amdgcn_sched_barrier(0);
    __builtin_amdgcn_s_barrier();

    for (int T = 0; T < NTt; ++T) {
        const int buf = T & 1;
        PHASE(0, 0, { if (T + 1 < NTt) stageA(buf ^ 1, 1, T + 1); }, {});
        PHASE(0, 1, { if (T + 1 < NTt) stageB(buf ^ 1, 0, T + 1); }, {});
        PHASE(1, 1, { if (T + 2 < NTt) stageA(buf, 0, T + 2); }, {});
        PHASE(1, 0, { if (T + 2 < NTt) stageB(buf, 1, T + 2); },
              { if (T + 1 < NTt) {
                    if (T + 2 < NTt) asm volatile("s_waitcnt vmcnt(4)" ::: "memory");
                    else             asm volatile("s_waitcnt vmcnt(0)" ::: "memory");
                    __builtin_amdgcn_sched_barrier(0);
                } });
    }

    // ---- epilogue: C/D layout col=lane&15, row=(lane>>4)*4+rj
    const int erow = m0 + wm * 64 + l4 * 4;
    const int ecol = n0 + wn * 32 + (lane & 15);
    _Float16* Cp = (_Float16*)C + (EPILOGUE == 2 ? (size_t)blockIdx.z * M * ldc : 0);
#pragma unroll
    for (int qr = 0; qr < 2; qr++)
#pragma unroll
        for (int qc = 0; qc < 2; qc++)
#pragma unroll
            for (int fr = 0; fr < 4; fr++)
#pragma unroll
                for (int fc = 0; fc < 2; fc++) {
                    const int col = ecol + qc * 128 + fc * 16;
#pragma unroll
                    for (int rj = 0; rj < 4; rj++) {
                        const int row = erow + qr * 128 + fr * 16 + rj;
                        float v = acc[qr][qc][fr][fc][rj];
                        if (EPILOGUE == 1) {
                            float bb = (col < NODES) ? bias[col] : 0.f;
                            float z = v + bb;
                            Cp[(size_t)row * ldc + col] =
                                (_Float16)(1.f / (1.f + __expf(-z)));
                        } else {
                            Cp[(size_t)row * ldc + col] = (_Float16)v;
                        }
                    }
                }
}

// ---------- reduce 4 fp16 partials -> f32 out ----------
__global__ void k_reduce4(const _Float16* __restrict__ part, float* __restrict__ out) {
    const size_t S = (size_t)BATCH * NOUT;
    size_t i = ((size_t)blockIdx.x * 256 + threadIdx.x) * 8;
    half8 a = *(const half8*)(part + i);
    half8 b = *(const half8*)(part + S + i);
    half8 c = *(const half8*)(part + 2 * S + i);
    half8 d = *(const half8*)(part + 3 * S + i);
    float4 lo, hi;
    lo.x = (float)a[0] + (float)b[0] + (float)c[0] + (float)d[0];
    lo.y = (float)a[1] + (float)b[1] + (float)c[1] + (float)d[1];
    lo.z = (float)a[2] + (float)b[2] + (float)c[2] + (float)d[2];
    lo.w = (float)a[3] + (float)b[3] + (float)c[3] + (float)d[3];
    hi.x = (float)a[4] + (float)b[4] + (float)c[4] + (float)d[4];
    hi.y = (float)a[5] + (float)b[5] + (float)c[5] + (float)d[5];
    hi.z = (float)a[6] + (float)b[6] + (float)c[6] + (float)d[6];
    hi.w = (float)a[7] + (float)b[7] + (float)c[7] + (float)d[7];
    *(float4*)(out + i) = lo;
    *(float4*)(out + i + 4) = hi;
}

// ---------- probs: per batch row, hierarchical tree-product expansion ----------
__global__ void k_probs(const _Float16* __restrict__ g,
                        _Float16* __restrict__ probs) {
    __shared__ float gs[NPAD];
    const int b = blockIdx.x;
    const _Float16* grow = g + (size_t)b * NPAD;
#pragma unroll
    for (int it = 0; it < 2; it++) {
        int i = threadIdx.x + it * 256;   // i in [0,512): 8 halves each
        half8 v = *(const half8*)(grow + i * 8);
#pragma unroll
        for (int j = 0; j < 8; j++) gs[i * 8 + j] = (float)v[j];
    }
    __syncthreads();
    const int t = threadIdx.x;  // subtree over leaves [t*16, t*16+16)
    float p = 1.f;
#pragma unroll
    for (int d = 0; d < 8; d++) {
        int node = (1 << d) - 1 + (t >> (8 - d));
        float gg = gs[node];
        int bit = (t >> (7 - d)) & 1;
        p *= bit ? gg : (1.f - gg);
    }
    float p9[2], p10[4], p11[8], p12[16];
    {
        float gg = gs[255 + t];
        p9[0] = p * (1.f - gg); p9[1] = p * gg;
    }
#pragma unroll
    for (int i = 0; i < 2; i++) {
        float gg = gs[511 + 2 * t + i];
        p10[2 * i] = p9[i] * (1.f - gg); p10[2 * i + 1] = p9[i] * gg;
    }
#pragma unroll
    for (int i = 0; i < 4; i++) {
        float gg = gs[1023 + 4 * t + i];
        p11[2 * i] = p10[i] * (1.f - gg); p11[2 * i + 1] = p10[i] * gg;
    }
#pragma unroll
    for (int i = 0; i < 8; i++) {
        float gg = gs[2047 + 8 * t + i];
        p12[2 * i] = p11[i] * (1.f - gg); p12[2 * i + 1] = p11[i] * gg;
    }
    half8 o0, o1;
#pragma unroll
    for (int j = 0; j < 8; j++) { o0[j] = (_Float16)p12[j]; o1[j] = (_Float16)p12[8 + j]; }
    _Float16* pr = probs + (size_t)b * NLEAF + t * 16;
    *(half8*)(pr) = o0;
    *(half8*)(pr + 8) = o1;
}

extern "C" void kernel_launch(void* const* d_in, const int* in_sizes, int n_in,
                              void* d_out, int out_size, void* d_ws, size_t ws_size,
                              hipStream_t stream) {
    (void)in_sizes; (void)n_in; (void)out_size; (void)ws_size;
    const float* x    = (const float*)d_in[0];
    const float* W    = (const float*)d_in[1];
    const float* bias = (const float*)d_in[2];
    const float* leaf = (const float*)d_in[3];
    float* out = (float*)d_out;

    // ws layout (halves). Long-lived first; partials alias the dead region.
    _Float16* base  = (_Float16*)d_ws;
    _Float16* leafT = base;                                   // [0,8) MB   live: transpose -> leaf GEMM
    _Float16* probs = base + (size_t)4 * 1024 * 1024;         // [8,40) MB  live: k_probs -> leaf GEMM
    _Float16* xh    = base + (size_t)20 * 1024 * 1024;        // [40,48) MB dead after gate GEMM
    _Float16* Wh    = base + (size_t)24 * 1024 * 1024;        // [48,56) MB dead after gate GEMM
    _Float16* g     = base + (size_t)28 * 1024 * 1024;        // [56,88) MB dead after k_probs
    _Float16* part  = xh;                                     // [40,72) MB written by leaf GEMM (after k_probs)

    k_f32_to_f16_pad<<<(BATCH * NIN / 4 + 255) / 256, 256, 0, stream>>>(
        x, xh, BATCH * NIN, BATCH * NIN);
    k_f32_to_f16_pad<<<(NPAD * NIN / 4 + 255) / 256, 256, 0, stream>>>(
        W, Wh, NPAD * NIN, NODES * NIN);
    k_transpose_f16<<<dim3(NLEAF / 32, NOUT / 32), 256, 0, stream>>>(leaf, leafT);

    gemm256<1><<<dim3(NPAD / 256, BATCH / 256, 1), 512, 0, stream>>>(
        xh, Wh, bias, (void*)g, BATCH, NPAD, NIN, NPAD, NIN);

    k_probs<<<BATCH, 256, 0, stream>>>(g, probs);

    gemm256<2><<<dim3(NOUT / 256, BATCH / 256, SPLITK), 512, 0, stream>>>(
        probs, leafT, nullptr, (void*)part, BATCH, NOUT, NLEAF, NOUT, NLEAF / SPLITK);

    k_reduce4<<<(BATCH * NOUT) / (256 * 8), 256, 0, stream>>>(part, out);
}

// Round 6
// 136.943 us; speedup vs baseline: 1.3416x; 1.0411x over previous
//
#include <hip/hip_runtime.h>
#include <hip/hip_bf16.h>
#include <hip/hip_fp16.h>

typedef _Float16 half8 __attribute__((ext_vector_type(8)));
typedef _Float16 half4 __attribute__((ext_vector_type(4)));
typedef float floatx4 __attribute__((ext_vector_type(4)));

#define BATCH   4096
#define NIN     1024
#define NODES   4095
#define NPAD    4096
#define NOUT    1024
#define NLEAF   4096
#define SPLITK  4

__device__ __forceinline__ void gload_lds16(const void* g, void* l) {
    __builtin_amdgcn_global_load_lds(
        (const __attribute__((address_space(1))) void*)g,
        (__attribute__((address_space(3))) void*)l, 16, 0, 0);
}

// ---------- convert f32 -> f16, zero-padding past nsrc ----------
__global__ void k_f32_to_f16_pad(const float* __restrict__ src,
                                 _Float16* __restrict__ dst, int n, int nsrc) {
    int i = (blockIdx.x * blockDim.x + threadIdx.x) * 4;
    if (i >= n) return;
    float4 v;
    if (i < nsrc) v = *(const float4*)(src + i);
    else          v = make_float4(0.f, 0.f, 0.f, 0.f);
    half4 h;
    h.x = (_Float16)v.x; h.y = (_Float16)v.y;
    h.z = (_Float16)v.z; h.w = (_Float16)v.w;
    *(half4*)(dst + i) = h;
}

// ---------- transpose leaf [NLEAF][NOUT] f32 -> leafT [NOUT][NLEAF] f16 ----------
__global__ void k_transpose_f16(const float* __restrict__ src,
                                _Float16* __restrict__ dst) {
    __shared__ _Float16 t[32][33];
    int l0 = blockIdx.x * 32, o0 = blockIdx.y * 32;
    int tx = threadIdx.x & 31, ty = threadIdx.x >> 5;  // 32 x 8
#pragma unroll
    for (int i = 0; i < 4; i++) {
        int l = l0 + ty + i * 8;
        t[ty + i * 8][tx] = (_Float16)src[(size_t)l * NOUT + o0 + tx];
    }
    __syncthreads();
#pragma unroll
    for (int i = 0; i < 4; i++) {
        int o = o0 + ty + i * 8;
        dst[(size_t)o * NLEAF + l0 + tx] = t[tx][ty + i * 8];
    }
}

// ================= 256x256 8-phase GEMM (C = A * B^T), f16 MFMA ================
// 8 waves (2M x 4N), per-wave output 128x64, INTERLEAVED rows:
//   rows = qr*128 + wm*64 + fr*16, cols = qc*128 + wn*32 + fc*16.
// Gray-code quadrant phases (0,0)(0,1)(1,1)(1,0) with REGISTER REUSE:
//   P1 reads af(qr=0)+bf0 (12 b128), P2 reads bf1 (4), P3 reads af(qr=1) (8),
//   P4 reads nothing -> 24 ds_read_b128 per K-tile (half of naive).
// Counted lgkm in P1/P3: kk0 operands gated by lgkmcnt(6)/(4); kk1 reads land
// under the kk0 MFMA cluster. Read-group order pinned by sched_barrier(0).
// Staging ring (1 half-tile per phase, 2 gload_lds/thread):
//   P1 -> (T+1).Ah1[buf^1], P2 -> (T+1).Bh0[buf^1],
//   P3 -> (T+2).Ah0[buf],   P4 -> (T+2).Bh1[buf]
// Gate at P4: vmcnt(4) == tile T+1 fully landed, T+2's 2 halves in flight.
// Overwrite safety: every phase that reads LDS hits lgkmcnt(0) inside the
// phase, and >=1 barrier separates those reads from the stage that overwrites.
// LDS chunk swizzle (both-sides, rule 21): chunk c of row r at pos c^(r&7);
// write side via pre-swizzled GLOBAL source (LDS dest linear), read same XOR.
// EPILOGUE==1: C fp16 = sigmoid(acc + bias[col])   (gate GEMM)
// EPILOGUE==2: C fp16 partial at C + z*M*ldc       (leaf GEMM split-K)
#define MFMA_CL(QR, QC, BARR, KK)                                               \
  _Pragma("unroll") for (int fr = 0; fr < 4; fr++)                              \
    _Pragma("unroll") for (int fc = 0; fc < 2; fc++)                            \
      acc[QR][QC][fr][fc] = __builtin_amdgcn_mfma_f32_16x16x32_f16(             \
          af[fr][KK], BARR[fc][KK], acc[QR][QC][fr][fc], 0, 0, 0);

template <int EPILOGUE>
__launch_bounds__(512, 2)
__global__ void gemm256(const _Float16* __restrict__ A,
                        const _Float16* __restrict__ Bm,
                        const float* __restrict__ bias,
                        void* __restrict__ C,
                        int M, int N, int K, int ldc, int Klen) {
    __shared__ __align__(16) _Float16 As[2][2][128 * 64];
    __shared__ __align__(16) _Float16 Bs[2][2][128 * 64];
    const int tid  = threadIdx.x;
    const int lane = tid & 63;
    const int wid  = tid >> 6;       // 0..7
    const int wm   = wid >> 2;       // 0..1
    const int wn   = wid & 3;        // 0..3
    const int m0 = blockIdx.y * 256;
    const int n0 = blockIdx.x * 256;
    const int k0 = blockIdx.z * Klen;
    (void)N;

    floatx4 acc[2][2][4][2] = {};
    half8 af[4][2];    // current A-quadrant fragments (qr=0 in P1-P2, qr=1 in P3-P4)
    half8 bf0[2][2];   // B quadrant qc=0 (loaded P1, used P1 & P4)
    half8 bf1[2][2];   // B quadrant qc=1 (loaded P2, used P2 & P3)

    // ---- staging geometry: thread stages 16B chunk tid (r=tid>>3,pos=tid&7)
    // and chunk tid+512 (row+64, same pos); source chunk pre-swizzled c=pos^(r&7).
    const int r1 = tid >> 3;
    const int c1 = (tid & 7) ^ (r1 & 7);
    const _Float16* Abase = A  + (size_t)(m0 + r1) * K + k0 + c1 * 8;
    const _Float16* Bbase = Bm + (size_t)(n0 + r1) * K + k0 + c1 * 8;

    auto stageA = [&](int bufx, int h, int T) {
        const _Float16* s = Abase + (size_t)h * 128 * K + T * 64;
        gload_lds16(s,                    &As[bufx][h][tid * 8]);
        gload_lds16(s + (size_t)64 * K,   &As[bufx][h][4096 + tid * 8]);
    };
    auto stageB = [&](int bufx, int h, int T) {
        const _Float16* s = Bbase + (size_t)h * 128 * K + T * 64;
        gload_lds16(s,                    &Bs[bufx][h][tid * 8]);
        gload_lds16(s + (size_t)64 * K,   &Bs[bufx][h][4096 + tid * 8]);
    };

    // ---- ds_read geometry: fragment row reads chunk c = kk*4 + (lane>>4)
    // at swizzled pos (c ^ (row&7)); row&7 invariant across fr (fr*16 % 8 == 0).
    const int l4   = lane >> 4;
    const int arow = wm * 64 + (lane & 15);
    const int brow = wn * 32 + (lane & 15);
    const int pA0 = ((l4)     ^ (arow & 7)) * 8;
    const int pA1 = ((4 + l4) ^ (arow & 7)) * 8;
    const int pB0 = ((l4)     ^ (brow & 7)) * 8;
    const int pB1 = ((4 + l4) ^ (brow & 7)) * 8;

    const int NTt = Klen >> 6;

    // ---- prologue: tile0 fully + tile1's {Ah0,Bh1}; leave tile1's pair in flight
    stageA(0, 0, 0); stageB(0, 0, 0); stageA(0, 1, 0); stageB(0, 1, 0);
    if (NTt > 1) {
        stageA(1, 0, 1); stageB(1, 1, 1);
        asm volatile("s_waitcnt vmcnt(4)" ::: "memory");
    } else {
        asm volatile("s_waitcnt vmcnt(0)" ::: "memory");
    }
    __builtin_amdgcn_sched_barrier(0);
    __builtin_amdgcn_s_barrier();

    for (int T = 0; T < NTt; ++T) {
        const int buf = T & 1;
        const _Float16* A0 = &As[buf][0][0];
        const _Float16* A1 = &As[buf][1][0];
        const _Float16* B0 = &Bs[buf][0][0];
        const _Float16* B1 = &Bs[buf][1][0];

        // ======== P1: q(0,0) — reads af(qr0)(8) + bf0(4); stage (T+1).Ah1
#pragma unroll
        for (int fr = 0; fr < 4; fr++)
            af[fr][0] = *(const half8*)(A0 + (arow + fr * 16) * 64 + pA0);
#pragma unroll
        for (int fc = 0; fc < 2; fc++)
            bf0[fc][0] = *(const half8*)(B0 + (brow + fc * 16) * 64 + pB0);
        __builtin_amdgcn_sched_barrier(0);   // pin kk0-group before kk1-group
#pragma unroll
        for (int fr = 0; fr < 4; fr++)
            af[fr][1] = *(const half8*)(A0 + (arow + fr * 16) * 64 + pA1);
#pragma unroll
        for (int fc = 0; fc < 2; fc++)
            bf0[fc][1] = *(const half8*)(B0 + (brow + fc * 16) * 64 + pB1);
        if (T + 1 < NTt) stageA(buf ^ 1, 1, T + 1);
        __builtin_amdgcn_s_barrier();
        asm volatile("s_waitcnt lgkmcnt(6)" ::: "memory");  // kk0 set ready
        __builtin_amdgcn_sched_barrier(0);
        __builtin_amdgcn_s_setprio(1);
        MFMA_CL(0, 0, bf0, 0);
        asm volatile("s_waitcnt lgkmcnt(0)" ::: "memory");
        __builtin_amdgcn_sched_barrier(0);
        MFMA_CL(0, 0, bf0, 1);
        __builtin_amdgcn_s_setprio(0);
        __builtin_amdgcn_s_barrier();

        // ======== P2: q(0,1) — reads bf1(4); af held; stage (T+1).Bh0
#pragma unroll
        for (int fc = 0; fc < 2; fc++)
            bf1[fc][0] = *(const half8*)(B1 + (brow + fc * 16) * 64 + pB0);
#pragma unroll
        for (int fc = 0; fc < 2; fc++)
            bf1[fc][1] = *(const half8*)(B1 + (brow + fc * 16) * 64 + pB1);
        if (T + 1 < NTt) stageB(buf ^ 1, 0, T + 1);
        __builtin_amdgcn_s_barrier();
        asm volatile("s_waitcnt lgkmcnt(0)" ::: "memory");
        __builtin_amdgcn_sched_barrier(0);
        __builtin_amdgcn_s_setprio(1);
        MFMA_CL(0, 1, bf1, 0);
        MFMA_CL(0, 1, bf1, 1);
        __builtin_amdgcn_s_setprio(0);
        __builtin_amdgcn_s_barrier();

        // ======== P3: q(1,1) — reads af(qr1)(8); bf1 held; stage (T+2).Ah0
#pragma unroll
        for (int fr = 0; fr < 4; fr++)
            af[fr][0] = *(const half8*)(A1 + (arow + fr * 16) * 64 + pA0);
        __builtin_amdgcn_sched_barrier(0);   // pin kk0-group first
#pragma unroll
        for (int fr = 0; fr < 4; fr++)
            af[fr][1] = *(const half8*)(A1 + (arow + fr * 16) * 64 + pA1);
        if (T + 2 < NTt) stageA(buf, 0, T + 2);
        __builtin_amdgcn_s_barrier();
        asm volatile("s_waitcnt lgkmcnt(4)" ::: "memory");  // af kk0 ready
        __builtin_amdgcn_sched_barrier(0);
        __builtin_amdgcn_s_setprio(1);
        MFMA_CL(1, 1, bf1, 0);
        asm volatile("s_waitcnt lgkmcnt(0)" ::: "memory");
        __builtin_amdgcn_sched_barrier(0);
        MFMA_CL(1, 1, bf1, 1);
        __builtin_amdgcn_s_setprio(0);
        __builtin_amdgcn_s_barrier();

        // ======== P4: q(1,0) — no reads (af,bf0 held); stage (T+2).Bh1; gate
        if (T + 2 < NTt) stageB(buf, 1, T + 2);
        __builtin_amdgcn_s_barrier();
        __builtin_amdgcn_s_setprio(1);
        MFMA_CL(1, 0, bf0, 0);
        MFMA_CL(1, 0, bf0, 1);
        __builtin_amdgcn_s_setprio(0);
        if (T + 1 < NTt) {
            if (T + 2 < NTt) asm volatile("s_waitcnt vmcnt(4)" ::: "memory");
            else             asm volatile("s_waitcnt vmcnt(0)" ::: "memory");
            __builtin_amdgcn_sched_barrier(0);
        }
        __builtin_amdgcn_s_barrier();
    }

    // ---- epilogue: C/D layout col=lane&15, row=(lane>>4)*4+rj
    const int erow = m0 + wm * 64 + l4 * 4;
    const int ecol = n0 + wn * 32 + (lane & 15);
    _Float16* Cp = (_Float16*)C + (EPILOGUE == 2 ? (size_t)blockIdx.z * M * ldc : 0);
#pragma unroll
    for (int qr = 0; qr < 2; qr++)
#pragma unroll
        for (int qc = 0; qc < 2; qc++)
#pragma unroll
            for (int fr = 0; fr < 4; fr++)
#pragma unroll
                for (int fc = 0; fc < 2; fc++) {
                    const int col = ecol + qc * 128 + fc * 16;
#pragma unroll
                    for (int rj = 0; rj < 4; rj++) {
                        const int row = erow + qr * 128 + fr * 16 + rj;
                        float v = acc[qr][qc][fr][fc][rj];
                        if (EPILOGUE == 1) {
                            float bb = (col < NODES) ? bias[col] : 0.f;
                            float z = v + bb;
                            Cp[(size_t)row * ldc + col] =
                                (_Float16)(1.f / (1.f + __expf(-z)));
                        } else {
                            Cp[(size_t)row * ldc + col] = (_Float16)v;
                        }
                    }
                }
}

// ---------- reduce 4 fp16 partials -> f32 out ----------
__global__ void k_reduce4(const _Float16* __restrict__ part, float* __restrict__ out) {
    const size_t S = (size_t)BATCH * NOUT;
    size_t i = ((size_t)blockIdx.x * 256 + threadIdx.x) * 8;
    half8 a = *(const half8*)(part + i);
    half8 b = *(const half8*)(part + S + i);
    half8 c = *(const half8*)(part + 2 * S + i);
    half8 d = *(const half8*)(part + 3 * S + i);
    float4 lo, hi;
    lo.x = (float)a[0] + (float)b[0] + (float)c[0] + (float)d[0];
    lo.y = (float)a[1] + (float)b[1] + (float)c[1] + (float)d[1];
    lo.z = (float)a[2] + (float)b[2] + (float)c[2] + (float)d[2];
    lo.w = (float)a[3] + (float)b[3] + (float)c[3] + (float)d[3];
    hi.x = (float)a[4] + (float)b[4] + (float)c[4] + (float)d[4];
    hi.y = (float)a[5] + (float)b[5] + (float)c[5] + (float)d[5];
    hi.z = (float)a[6] + (float)b[6] + (float)c[6] + (float)d[6];
    hi.w = (float)a[7] + (float)b[7] + (float)c[7] + (float)d[7];
    *(float4*)(out + i) = lo;
    *(float4*)(out + i + 4) = hi;
}

// ---------- probs: per batch row, hierarchical tree-product expansion ----------
__global__ void k_probs(const _Float16* __restrict__ g,
                        _Float16* __restrict__ probs) {
    __shared__ float gs[NPAD];
    const int b = blockIdx.x;
    const _Float16* grow = g + (size_t)b * NPAD;
#pragma unroll
    for (int it = 0; it < 2; it++) {
        int i = threadIdx.x + it * 256;   // i in [0,512): 8 halves each
        half8 v = *(const half8*)(grow + i * 8);
#pragma unroll
        for (int j = 0; j < 8; j++) gs[i * 8 + j] = (float)v[j];
    }
    __syncthreads();
    const int t = threadIdx.x;  // subtree over leaves [t*16, t*16+16)
    float p = 1.f;
#pragma unroll
    for (int d = 0; d < 8; d++) {
        int node = (1 << d) - 1 + (t >> (8 - d));
        float gg = gs[node];
        int bit = (t >> (7 - d)) & 1;
        p *= bit ? gg : (1.f - gg);
    }
    float p9[2], p10[4], p11[8], p12[16];
    {
        float gg = gs[255 + t];
        p9[0] = p * (1.f - gg); p9[1] = p * gg;
    }
#pragma unroll
    for (int i = 0; i < 2; i++) {
        float gg = gs[511 + 2 * t + i];
        p10[2 * i] = p9[i] * (1.f - gg); p10[2 * i + 1] = p9[i] * gg;
    }
#pragma unroll
    for (int i = 0; i < 4; i++) {
        float gg = gs[1023 + 4 * t + i];
        p11[2 * i] = p10[i] * (1.f - gg); p11[2 * i + 1] = p10[i] * gg;
    }
#pragma unroll
    for (int i = 0; i < 8; i++) {
        float gg = gs[2047 + 8 * t + i];
        p12[2 * i] = p11[i] * (1.f - gg); p12[2 * i + 1] = p11[i] * gg;
    }
    half8 o0, o1;
#pragma unroll
    for (int j = 0; j < 8; j++) { o0[j] = (_Float16)p12[j]; o1[j] = (_Float16)p12[8 + j]; }
    _Float16* pr = probs + (size_t)b * NLEAF + t * 16;
    *(half8*)(pr) = o0;
    *(half8*)(pr + 8) = o1;
}

extern "C" void kernel_launch(void* const* d_in, const int* in_sizes, int n_in,
                              void* d_out, int out_size, void* d_ws, size_t ws_size,
                              hipStream_t stream) {
    (void)in_sizes; (void)n_in; (void)out_size; (void)ws_size;
    const float* x    = (const float*)d_in[0];
    const float* W    = (const float*)d_in[1];
    const float* bias = (const float*)d_in[2];
    const float* leaf = (const float*)d_in[3];
    float* out = (float*)d_out;

    // ws layout (halves). Long-lived first; partials alias the dead region.
    _Float16* base  = (_Float16*)d_ws;
    _Float16* leafT = base;                                   // [0,8) MB   live: transpose -> leaf GEMM
    _Float16* probs = base + (size_t)4 * 1024 * 1024;         // [8,40) MB  live: k_probs -> leaf GEMM
    _Float16* xh    = base + (size_t)20 * 1024 * 1024;        // [40,48) MB dead after gate GEMM
    _Float16* Wh    = base + (size_t)24 * 1024 * 1024;        // [48,56) MB dead after gate GEMM
    _Float16* g     = base + (size_t)28 * 1024 * 1024;        // [56,88) MB dead after k_probs
    _Float16* part  = xh;                                     // [40,72) MB written by leaf GEMM (after k_probs)

    k_f32_to_f16_pad<<<(BATCH * NIN / 4 + 255) / 256, 256, 0, stream>>>(
        x, xh, BATCH * NIN, BATCH * NIN);
    k_f32_to_f16_pad<<<(NPAD * NIN / 4 + 255) / 256, 256, 0, stream>>>(
        W, Wh, NPAD * NIN, NODES * NIN);
    k_transpose_f16<<<dim3(NLEAF / 32, NOUT / 32), 256, 0, stream>>>(leaf, leafT);

    gemm256<1><<<dim3(NPAD / 256, BATCH / 256, 1), 512, 0, stream>>>(
        xh, Wh, bias, (void*)g, BATCH, NPAD, NIN, NPAD, NIN);

    k_probs<<<BATCH, 256, 0, stream>>>(g, probs);

    gemm256<2><<<dim3(NOUT / 256, BATCH / 256, SPLITK), 512, 0, stream>>>(
        probs, leafT, nullptr, (void*)part, BATCH, NOUT, NLEAF, NOUT, NLEAF / SPLITK);

    k_reduce4<<<(BATCH * NOUT) / (256 * 8), 256, 0, stream>>>(part, out);
}